// Round 7
// baseline (67.142 us; speedup 1.0000x reference)
//
#include <hip/hip_runtime.h>

#define GAMMA 0.5f
#define SMOOTH 1.0f
#define MB_BLOCKS 1024
#define NCONTOUR 64
#define CHUNK 8

typedef float f32x4 __attribute__((ext_vector_type(4)));

// ---------------------------------------------------------------------------
// Mask-path body (MLP schedule): 24 independent loads in flight per thread.
// PLAIN loads (no nontemporal): graph replays are warm, so the 201 MB of
// masks stays Infinity-Cache-resident across replays -> L3-BW stream.
// __noinline__ isolates scheduling/regalloc from the contour branch.
// ---------------------------------------------------------------------------
__device__ __attribute__((noinline)) void mask_sums_body(
    const f32x4* __restrict__ g4, const f32x4* __restrict__ s4,
    const f32x4* __restrict__ c4, float* __restrict__ psum,
    int mbid, int iters)
{
    float s_cg = 0.f, s_cs = 0.f, s_c = 0.f, s_g = 0.f, s_s = 0.f;
    const int span = 256 * CHUNK;                 // float4s per block per iter
    int base0 = mbid * (iters * span) + threadIdx.x;

    for (int it = 0; it < iters; ++it) {
        int base = base0 + it * span;
        f32x4 g[CHUNK], s[CHUNK], c[CHUNK];
#pragma unroll
        for (int k = 0; k < CHUNK; ++k) g[k] = g4[base + k * 256];
#pragma unroll
        for (int k = 0; k < CHUNK; ++k) s[k] = s4[base + k * 256];
#pragma unroll
        for (int k = 0; k < CHUNK; ++k) c[k] = c4[base + k * 256];

#pragma unroll
        for (int k = 0; k < CHUNK; ++k) {
            s_cg += c[k].x * g[k].x + c[k].y * g[k].y + c[k].z * g[k].z + c[k].w * g[k].w;
            s_cs += c[k].x * s[k].x + c[k].y * s[k].y + c[k].z * s[k].z + c[k].w * s[k].w;
            s_c  += c[k].x + c[k].y + c[k].z + c[k].w;
            s_g  += g[k].x + g[k].y + g[k].z + g[k].w;
            s_s  += s[k].x + s[k].y + s[k].z + s[k].w;
        }
    }

#pragma unroll
    for (int off = 32; off > 0; off >>= 1) {
        s_cg += __shfl_down(s_cg, off);
        s_cs += __shfl_down(s_cs, off);
        s_c  += __shfl_down(s_c,  off);
        s_g  += __shfl_down(s_g,  off);
        s_s  += __shfl_down(s_s,  off);
    }
    __shared__ float red[4][5];
    int lane = threadIdx.x & 63;
    int wid  = threadIdx.x >> 6;
    if (lane == 0) {
        red[wid][0] = s_cg; red[wid][1] = s_cs; red[wid][2] = s_c;
        red[wid][3] = s_g;  red[wid][4] = s_s;
    }
    __syncthreads();
    if (threadIdx.x == 0) {
#pragma unroll
        for (int k = 0; k < 5; ++k) {
            float a = red[0][k] + red[1][k] + red[2][k] + red[3][k];
            psum[k * MB_BLOCKS + mbid] = a;
        }
    }
}

// ---------------------------------------------------------------------------
// Contour-path body: per-batch cyclic-shift MSE minima (one block = batch b).
// ---------------------------------------------------------------------------
__device__ __attribute__((noinline)) void contour_body(
    const float2* __restrict__ gtc, const float2* __restrict__ sgs,
    const float2* __restrict__ scs, const float2* __restrict__ cc,
    float* __restrict__ seg_min, float* __restrict__ cons_min, int b)
{
    __shared__ float gx[256], gy[256];   // ground_truth_contour
    __shared__ float ax[256], ay[256];   // snake_GT_size
    __shared__ float px[256], py[256];   // snake_classic_size
    __shared__ float cx[256], cy[256];   // classic_contour
    int t = threadIdx.x;
    float2 v;
    v = gtc[b * 256 + t]; gx[t] = v.x; gy[t] = v.y;
    v = sgs[b * 256 + t]; ax[t] = v.x; ay[t] = v.y;
    v = scs[b * 256 + t]; px[t] = v.x; py[t] = v.y;
    v = cc [b * 256 + t]; cx[t] = v.x; cy[t] = v.y;
    __syncthreads();

    // shift-0 seg candidate compares snake_classic_size vs GT contour
    const float* sx = (t == 0) ? px : ax;
    const float* sy = (t == 0) ? py : ay;

    float seg = 0.f, cons = 0.f;
#pragma unroll 4
    for (int j = 0; j < 256; ++j) {
        int r = (j - t) & 255;
        float dx = sx[j] - gx[r];
        float dy = sy[j] - gy[r];
        seg += dx * dx + dy * dy;
        float ex = px[j] - cx[r];
        float ey = py[j] - cy[r];
        cons += ex * ex + ey * ey;
    }
    seg  *= (1.0f / 512.0f);
    cons *= (1.0f / 512.0f);

#pragma unroll
    for (int off = 32; off > 0; off >>= 1) {
        seg  = fminf(seg,  __shfl_down(seg,  off));
        cons = fminf(cons, __shfl_down(cons, off));
    }
    __shared__ float rs[4], rc[4];
    int lane = t & 63, wid = t >> 6;
    if (lane == 0) { rs[wid] = seg; rc[wid] = cons; }
    __syncthreads();
    if (t == 0) {
        seg_min[b]  = fminf(fminf(rs[0], rs[1]), fminf(rs[2], rs[3]));
        cons_min[b] = fminf(fminf(rc[0], rc[1]), fminf(rc[2], rc[3]));
    }
}

// ---------------------------------------------------------------------------
// Kernel A (fused): blocks [0, NCONTOUR) do contour minima; blocks
// [NCONTOUR, NCONTOUR+MB_BLOCKS) do the 5-way mask sums.
// __launch_bounds__(256, 8): 8 blocks/CU -> all 1088 blocks co-resident
// (no straggler tail), 32 waves/CU of latency hiding. VGPR cap 64
// (compiler used 60 at this schedule in R6).
// ---------------------------------------------------------------------------
__global__ __launch_bounds__(256, 8) void fused_kernel(
    const f32x4* __restrict__ g4, const f32x4* __restrict__ s4,
    const f32x4* __restrict__ c4,
    const float2* __restrict__ gtc, const float2* __restrict__ sgs,
    const float2* __restrict__ scs, const float2* __restrict__ cc,
    float* __restrict__ psum, float* __restrict__ seg_min,
    float* __restrict__ cons_min, int iters)
{
    int bid = blockIdx.x;
    if (bid < NCONTOUR) {
        contour_body(gtc, sgs, scs, cc, seg_min, cons_min, bid);
    } else {
        mask_sums_body(g4, s4, c4, psum, bid - NCONTOUR, iters);
    }
}

// ---------------------------------------------------------------------------
// Kernel B: finalize. One combined 7-value reduction (5 mask sums + seg +
// cons), then compose the scalar loss.
// ---------------------------------------------------------------------------
__global__ __launch_bounds__(256) void final_kernel(
    const float* __restrict__ psum, const float* __restrict__ seg_min,
    const float* __restrict__ cons_min, float* __restrict__ out, int B)
{
    int t = threadIdx.x;
    float v[7] = {0.f, 0.f, 0.f, 0.f, 0.f, 0.f, 0.f};

#pragma unroll
    for (int k = 0; k < 5; ++k)
        for (int i = t; i < MB_BLOCKS; i += 256)
            v[k] += psum[k * MB_BLOCKS + i];
    if (t < B) { v[5] = seg_min[t]; v[6] = cons_min[t]; }

#pragma unroll
    for (int off = 32; off > 0; off >>= 1) {
#pragma unroll
        for (int k = 0; k < 7; ++k) v[k] += __shfl_down(v[k], off);
    }
    __shared__ float red[4][7];
    int lane = t & 63, wid = t >> 6;
    if (lane == 0) {
#pragma unroll
        for (int k = 0; k < 7; ++k) red[wid][k] = v[k];
    }
    __syncthreads();
    if (t == 0) {
        float tot[7];
#pragma unroll
        for (int k = 0; k < 7; ++k)
            tot[k] = red[0][k] + red[1][k] + red[2][k] + red[3][k];
        float S_cg = tot[0], S_cs = tot[1], S_c = tot[2],
              S_g  = tot[3], S_s  = tot[4];
        float seg_tot = tot[5], cons_tot = tot[6];
        float dice1 = 1.f - (2.f * S_cg + SMOOTH) / (S_c + S_g + SMOOTH);
        float dice2 = 1.f - (2.f * S_cs + SMOOTH) / (S_c + S_s + SMOOTH);
        out[0] = dice1 + seg_tot + GAMMA * (dice2 + cons_tot);
    }
}

extern "C" void kernel_launch(void* const* d_in, const int* in_sizes, int n_in,
                              void* d_out, int out_size, void* d_ws, size_t ws_size,
                              hipStream_t stream) {
    const float* gt_mask = (const float*)d_in[0];   // [B,512,512]
    const float* gtc     = (const float*)d_in[1];   // [B,256,2]
    const float* sgs     = (const float*)d_in[2];   // [B,256,2]
    const float* scs     = (const float*)d_in[3];   // [B,256,2]
    const float* sn_mask = (const float*)d_in[4];   // [B,512,512]
    const float* cc      = (const float*)d_in[5];   // [B,256,2]
    const float* cl_mask = (const float*)d_in[6];   // [B,512,512]
    float* out = (float*)d_out;

    int n4    = in_sizes[0] / 4;                    // 4,194,304 float4s
    int iters = n4 / (MB_BLOCKS * 256 * CHUNK);     // 2
    int B     = in_sizes[1] / 512;                  // 64

    float* ws       = (float*)d_ws;
    float* psum     = ws;                           // 5 * MB_BLOCKS floats
    float* seg_min  = ws + 5 * MB_BLOCKS;           // B floats
    float* cons_min = seg_min + 64;                 // B floats

    hipLaunchKernelGGL(fused_kernel, dim3(MB_BLOCKS + NCONTOUR), dim3(256), 0, stream,
                       (const f32x4*)gt_mask, (const f32x4*)sn_mask,
                       (const f32x4*)cl_mask,
                       (const float2*)gtc, (const float2*)sgs,
                       (const float2*)scs, (const float2*)cc,
                       psum, seg_min, cons_min, iters);
    hipLaunchKernelGGL(final_kernel, dim3(1), dim3(256), 0, stream,
                       psum, seg_min, cons_min, out, B);
}

// Round 8
// 58.730 us; speedup vs baseline: 1.1432x; 1.1432x over previous
//
#include <hip/hip_runtime.h>

#define GAMMA 0.5f
#define SMOOTH 1.0f
#define MB_BLOCKS 1024
#define NCONTOUR 64
#define CHUNK 8

typedef float f32x4 __attribute__((ext_vector_type(4)));

// ---------------------------------------------------------------------------
// Mask-path body: PLAIN loads (L3 retains all 201 MB across graph replays;
// R2/R5 evidence) + sched_group_barrier to force the 24-deep load cluster
// the compiler otherwise abandons with plain loads (R4/R7 evidence:
// VGPR~32 interleave). Emission order pinned per iteration:
//   ~16 addr-VALU -> 24 VMEM_READ -> FMA block.
// __noinline__ isolates scheduling/regalloc from the contour branch.
// ---------------------------------------------------------------------------
__device__ __attribute__((noinline)) void mask_sums_body(
    const f32x4* __restrict__ g4, const f32x4* __restrict__ s4,
    const f32x4* __restrict__ c4, float* __restrict__ psum,
    int mbid, int iters)
{
    float s_cg = 0.f, s_cs = 0.f, s_c = 0.f, s_g = 0.f, s_s = 0.f;
    const int span = 256 * CHUNK;                 // float4s per block per iter
    int base0 = mbid * (iters * span) + threadIdx.x;

    for (int it = 0; it < iters; ++it) {
        int base = base0 + it * span;
        f32x4 g[CHUNK], s[CHUNK], c[CHUNK];
#pragma unroll
        for (int k = 0; k < CHUNK; ++k) g[k] = g4[base + k * 256];
#pragma unroll
        for (int k = 0; k < CHUNK; ++k) s[k] = s4[base + k * 256];
#pragma unroll
        for (int k = 0; k < CHUNK; ++k) c[k] = c4[base + k * 256];

#pragma unroll
        for (int k = 0; k < CHUNK; ++k) {
            s_cg += c[k].x * g[k].x + c[k].y * g[k].y + c[k].z * g[k].z + c[k].w * g[k].w;
            s_cs += c[k].x * s[k].x + c[k].y * s[k].y + c[k].z * s[k].z + c[k].w * s[k].w;
            s_c  += c[k].x + c[k].y + c[k].z + c[k].w;
            s_g  += g[k].x + g[k].y + g[k].z + g[k].w;
            s_s  += s[k].x + s[k].y + s[k].z + s[k].w;
        }

        // T19: pin the schedule -- address VALU, then ALL 24 loads
        // back-to-back (MLP), then the FMA block.
        __builtin_amdgcn_sched_group_barrier(0x002, 16, 0);   // VALU (addr)
        __builtin_amdgcn_sched_group_barrier(0x020, 24, 0);   // VMEM_READ x24
        __builtin_amdgcn_sched_group_barrier(0x002, 200, 0);  // VALU (FMAs)
    }

#pragma unroll
    for (int off = 32; off > 0; off >>= 1) {
        s_cg += __shfl_down(s_cg, off);
        s_cs += __shfl_down(s_cs, off);
        s_c  += __shfl_down(s_c,  off);
        s_g  += __shfl_down(s_g,  off);
        s_s  += __shfl_down(s_s,  off);
    }
    __shared__ float red[4][5];
    int lane = threadIdx.x & 63;
    int wid  = threadIdx.x >> 6;
    if (lane == 0) {
        red[wid][0] = s_cg; red[wid][1] = s_cs; red[wid][2] = s_c;
        red[wid][3] = s_g;  red[wid][4] = s_s;
    }
    __syncthreads();
    if (threadIdx.x == 0) {
#pragma unroll
        for (int k = 0; k < 5; ++k) {
            float a = red[0][k] + red[1][k] + red[2][k] + red[3][k];
            psum[k * MB_BLOCKS + mbid] = a;
        }
    }
}

// ---------------------------------------------------------------------------
// Contour-path body: per-batch cyclic-shift MSE minima (one block = batch b).
// ---------------------------------------------------------------------------
__device__ __attribute__((noinline)) void contour_body(
    const float2* __restrict__ gtc, const float2* __restrict__ sgs,
    const float2* __restrict__ scs, const float2* __restrict__ cc,
    float* __restrict__ seg_min, float* __restrict__ cons_min, int b)
{
    __shared__ float gx[256], gy[256];   // ground_truth_contour
    __shared__ float ax[256], ay[256];   // snake_GT_size
    __shared__ float px[256], py[256];   // snake_classic_size
    __shared__ float cx[256], cy[256];   // classic_contour
    int t = threadIdx.x;
    float2 v;
    v = gtc[b * 256 + t]; gx[t] = v.x; gy[t] = v.y;
    v = sgs[b * 256 + t]; ax[t] = v.x; ay[t] = v.y;
    v = scs[b * 256 + t]; px[t] = v.x; py[t] = v.y;
    v = cc [b * 256 + t]; cx[t] = v.x; cy[t] = v.y;
    __syncthreads();

    // shift-0 seg candidate compares snake_classic_size vs GT contour
    const float* sx = (t == 0) ? px : ax;
    const float* sy = (t == 0) ? py : ay;

    float seg = 0.f, cons = 0.f;
#pragma unroll 4
    for (int j = 0; j < 256; ++j) {
        int r = (j - t) & 255;
        float dx = sx[j] - gx[r];
        float dy = sy[j] - gy[r];
        seg += dx * dx + dy * dy;
        float ex = px[j] - cx[r];
        float ey = py[j] - cy[r];
        cons += ex * ex + ey * ey;
    }
    seg  *= (1.0f / 512.0f);
    cons *= (1.0f / 512.0f);

#pragma unroll
    for (int off = 32; off > 0; off >>= 1) {
        seg  = fminf(seg,  __shfl_down(seg,  off));
        cons = fminf(cons, __shfl_down(cons, off));
    }
    __shared__ float rs[4], rc[4];
    int lane = t & 63, wid = t >> 6;
    if (lane == 0) { rs[wid] = seg; rc[wid] = cons; }
    __syncthreads();
    if (t == 0) {
        seg_min[b]  = fminf(fminf(rs[0], rs[1]), fminf(rs[2], rs[3]));
        cons_min[b] = fminf(fminf(rc[0], rc[1]), fminf(rc[2], rc[3]));
    }
}

// ---------------------------------------------------------------------------
// Kernel A (fused): blocks [0, NCONTOUR) do contour minima; blocks
// [NCONTOUR, NCONTOUR+MB_BLOCKS) do the 5-way mask sums.
// __launch_bounds__(256, 4): 128-VGPR cap -- room for 24 live float4s,
// no spill (R7 lesson: (256,8) spills).
// ---------------------------------------------------------------------------
__global__ __launch_bounds__(256, 4) void fused_kernel(
    const f32x4* __restrict__ g4, const f32x4* __restrict__ s4,
    const f32x4* __restrict__ c4,
    const float2* __restrict__ gtc, const float2* __restrict__ sgs,
    const float2* __restrict__ scs, const float2* __restrict__ cc,
    float* __restrict__ psum, float* __restrict__ seg_min,
    float* __restrict__ cons_min, int iters)
{
    int bid = blockIdx.x;
    if (bid < NCONTOUR) {
        contour_body(gtc, sgs, scs, cc, seg_min, cons_min, bid);
    } else {
        mask_sums_body(g4, s4, c4, psum, bid - NCONTOUR, iters);
    }
}

// ---------------------------------------------------------------------------
// Kernel B: finalize. One combined 7-value reduction (5 mask sums + seg +
// cons), then compose the scalar loss.
// ---------------------------------------------------------------------------
__global__ __launch_bounds__(256) void final_kernel(
    const float* __restrict__ psum, const float* __restrict__ seg_min,
    const float* __restrict__ cons_min, float* __restrict__ out, int B)
{
    int t = threadIdx.x;
    float v[7] = {0.f, 0.f, 0.f, 0.f, 0.f, 0.f, 0.f};

#pragma unroll
    for (int k = 0; k < 5; ++k)
        for (int i = t; i < MB_BLOCKS; i += 256)
            v[k] += psum[k * MB_BLOCKS + i];
    if (t < B) { v[5] = seg_min[t]; v[6] = cons_min[t]; }

#pragma unroll
    for (int off = 32; off > 0; off >>= 1) {
#pragma unroll
        for (int k = 0; k < 7; ++k) v[k] += __shfl_down(v[k], off);
    }
    __shared__ float red[4][7];
    int lane = t & 63, wid = t >> 6;
    if (lane == 0) {
#pragma unroll
        for (int k = 0; k < 7; ++k) red[wid][k] = v[k];
    }
    __syncthreads();
    if (t == 0) {
        float tot[7];
#pragma unroll
        for (int k = 0; k < 7; ++k)
            tot[k] = red[0][k] + red[1][k] + red[2][k] + red[3][k];
        float S_cg = tot[0], S_cs = tot[1], S_c = tot[2],
              S_g  = tot[3], S_s  = tot[4];
        float seg_tot = tot[5], cons_tot = tot[6];
        float dice1 = 1.f - (2.f * S_cg + SMOOTH) / (S_c + S_g + SMOOTH);
        float dice2 = 1.f - (2.f * S_cs + SMOOTH) / (S_c + S_s + SMOOTH);
        out[0] = dice1 + seg_tot + GAMMA * (dice2 + cons_tot);
    }
}

extern "C" void kernel_launch(void* const* d_in, const int* in_sizes, int n_in,
                              void* d_out, int out_size, void* d_ws, size_t ws_size,
                              hipStream_t stream) {
    const float* gt_mask = (const float*)d_in[0];   // [B,512,512]
    const float* gtc     = (const float*)d_in[1];   // [B,256,2]
    const float* sgs     = (const float*)d_in[2];   // [B,256,2]
    const float* scs     = (const float*)d_in[3];   // [B,256,2]
    const float* sn_mask = (const float*)d_in[4];   // [B,512,512]
    const float* cc      = (const float*)d_in[5];   // [B,256,2]
    const float* cl_mask = (const float*)d_in[6];   // [B,512,512]
    float* out = (float*)d_out;

    int n4    = in_sizes[0] / 4;                    // 4,194,304 float4s
    int iters = n4 / (MB_BLOCKS * 256 * CHUNK);     // 2
    int B     = in_sizes[1] / 512;                  // 64

    float* ws       = (float*)d_ws;
    float* psum     = ws;                           // 5 * MB_BLOCKS floats
    float* seg_min  = ws + 5 * MB_BLOCKS;           // B floats
    float* cons_min = seg_min + 64;                 // B floats

    hipLaunchKernelGGL(fused_kernel, dim3(MB_BLOCKS + NCONTOUR), dim3(256), 0, stream,
                       (const f32x4*)gt_mask, (const f32x4*)sn_mask,
                       (const f32x4*)cl_mask,
                       (const float2*)gtc, (const float2*)sgs,
                       (const float2*)scs, (const float2*)cc,
                       psum, seg_min, cons_min, iters);
    hipLaunchKernelGGL(final_kernel, dim3(1), dim3(256), 0, stream,
                       psum, seg_min, cons_min, out, B);
}

// Round 9
// 46.155 us; speedup vs baseline: 1.4547x; 1.2724x over previous
//
#include <hip/hip_runtime.h>

#define GAMMA 0.5f
#define SMOOTH 1.0f
#define MB_BLOCKS 2048
#define NCONTOUR 64
#define CHUNK 8

typedef float f32x4 __attribute__((ext_vector_type(4)));

// ---------------------------------------------------------------------------
// Mask-path body: single burst of 24 nontemporal loads (CHUNK=8 x 3 streams),
// then the FMA block, then reduce. No iters loop: one burst-drain per block,
// compiler free to hoist the whole load cluster (R3/R5-style codegen).
// __noinline__ isolates scheduling/regalloc from the contour branch.
// ---------------------------------------------------------------------------
__device__ __attribute__((noinline)) void mask_sums_body(
    const f32x4* __restrict__ g4, const f32x4* __restrict__ s4,
    const f32x4* __restrict__ c4, float* __restrict__ psum, int mbid)
{
    int base = mbid * (256 * CHUNK) + threadIdx.x;

    f32x4 g[CHUNK], s[CHUNK], c[CHUNK];
#pragma unroll
    for (int k = 0; k < CHUNK; ++k)
        g[k] = __builtin_nontemporal_load(&g4[base + k * 256]);
#pragma unroll
    for (int k = 0; k < CHUNK; ++k)
        s[k] = __builtin_nontemporal_load(&s4[base + k * 256]);
#pragma unroll
    for (int k = 0; k < CHUNK; ++k)
        c[k] = __builtin_nontemporal_load(&c4[base + k * 256]);

    float s_cg = 0.f, s_cs = 0.f, s_c = 0.f, s_g = 0.f, s_s = 0.f;
#pragma unroll
    for (int k = 0; k < CHUNK; ++k) {
        s_cg += c[k].x * g[k].x + c[k].y * g[k].y + c[k].z * g[k].z + c[k].w * g[k].w;
        s_cs += c[k].x * s[k].x + c[k].y * s[k].y + c[k].z * s[k].z + c[k].w * s[k].w;
        s_c  += c[k].x + c[k].y + c[k].z + c[k].w;
        s_g  += g[k].x + g[k].y + g[k].z + g[k].w;
        s_s  += s[k].x + s[k].y + s[k].z + s[k].w;
    }

#pragma unroll
    for (int off = 32; off > 0; off >>= 1) {
        s_cg += __shfl_down(s_cg, off);
        s_cs += __shfl_down(s_cs, off);
        s_c  += __shfl_down(s_c,  off);
        s_g  += __shfl_down(s_g,  off);
        s_s  += __shfl_down(s_s,  off);
    }
    __shared__ float red[4][5];
    int lane = threadIdx.x & 63;
    int wid  = threadIdx.x >> 6;
    if (lane == 0) {
        red[wid][0] = s_cg; red[wid][1] = s_cs; red[wid][2] = s_c;
        red[wid][3] = s_g;  red[wid][4] = s_s;
    }
    __syncthreads();
    if (threadIdx.x == 0) {
#pragma unroll
        for (int k = 0; k < 5; ++k) {
            float a = red[0][k] + red[1][k] + red[2][k] + red[3][k];
            psum[k * MB_BLOCKS + mbid] = a;
        }
    }
}

// ---------------------------------------------------------------------------
// Contour-path body: per-batch cyclic-shift MSE minima (one block = batch b).
// ---------------------------------------------------------------------------
__device__ __attribute__((noinline)) void contour_body(
    const float2* __restrict__ gtc, const float2* __restrict__ sgs,
    const float2* __restrict__ scs, const float2* __restrict__ cc,
    float* __restrict__ seg_min, float* __restrict__ cons_min, int b)
{
    __shared__ float gx[256], gy[256];   // ground_truth_contour
    __shared__ float ax[256], ay[256];   // snake_GT_size
    __shared__ float px[256], py[256];   // snake_classic_size
    __shared__ float cx[256], cy[256];   // classic_contour
    int t = threadIdx.x;
    float2 v;
    v = gtc[b * 256 + t]; gx[t] = v.x; gy[t] = v.y;
    v = sgs[b * 256 + t]; ax[t] = v.x; ay[t] = v.y;
    v = scs[b * 256 + t]; px[t] = v.x; py[t] = v.y;
    v = cc [b * 256 + t]; cx[t] = v.x; cy[t] = v.y;
    __syncthreads();

    // shift-0 seg candidate compares snake_classic_size vs GT contour
    const float* sx = (t == 0) ? px : ax;
    const float* sy = (t == 0) ? py : ay;

    float seg = 0.f, cons = 0.f;
#pragma unroll 4
    for (int j = 0; j < 256; ++j) {
        int r = (j - t) & 255;
        float dx = sx[j] - gx[r];
        float dy = sy[j] - gy[r];
        seg += dx * dx + dy * dy;
        float ex = px[j] - cx[r];
        float ey = py[j] - cy[r];
        cons += ex * ex + ey * ey;
    }
    seg  *= (1.0f / 512.0f);
    cons *= (1.0f / 512.0f);

#pragma unroll
    for (int off = 32; off > 0; off >>= 1) {
        seg  = fminf(seg,  __shfl_down(seg,  off));
        cons = fminf(cons, __shfl_down(cons, off));
    }
    __shared__ float rs[4], rc[4];
    int lane = t & 63, wid = t >> 6;
    if (lane == 0) { rs[wid] = seg; rc[wid] = cons; }
    __syncthreads();
    if (t == 0) {
        seg_min[b]  = fminf(fminf(rs[0], rs[1]), fminf(rs[2], rs[3]));
        cons_min[b] = fminf(fminf(rc[0], rc[1]), fminf(rc[2], rc[3]));
    }
}

// ---------------------------------------------------------------------------
// Kernel A (fused): blocks [0, NCONTOUR) do contour minima; blocks
// [NCONTOUR, NCONTOUR+MB_BLOCKS) do the 5-way mask sums (one burst each).
// __launch_bounds__(256, 4): 128-VGPR cap, no spill (R7/R8 lesson).
// ---------------------------------------------------------------------------
__global__ __launch_bounds__(256, 4) void fused_kernel(
    const f32x4* __restrict__ g4, const f32x4* __restrict__ s4,
    const f32x4* __restrict__ c4,
    const float2* __restrict__ gtc, const float2* __restrict__ sgs,
    const float2* __restrict__ scs, const float2* __restrict__ cc,
    float* __restrict__ psum, float* __restrict__ seg_min,
    float* __restrict__ cons_min)
{
    int bid = blockIdx.x;
    if (bid < NCONTOUR) {
        contour_body(gtc, sgs, scs, cc, seg_min, cons_min, bid);
    } else {
        mask_sums_body(g4, s4, c4, psum, bid - NCONTOUR);
    }
}

// ---------------------------------------------------------------------------
// Kernel B: finalize. One combined 7-value reduction (5 mask sums + seg +
// cons), then compose the scalar loss.
// ---------------------------------------------------------------------------
__global__ __launch_bounds__(256) void final_kernel(
    const float* __restrict__ psum, const float* __restrict__ seg_min,
    const float* __restrict__ cons_min, float* __restrict__ out, int B)
{
    int t = threadIdx.x;
    float v[7] = {0.f, 0.f, 0.f, 0.f, 0.f, 0.f, 0.f};

#pragma unroll
    for (int k = 0; k < 5; ++k)
        for (int i = t; i < MB_BLOCKS; i += 256)
            v[k] += psum[k * MB_BLOCKS + i];
    if (t < B) { v[5] = seg_min[t]; v[6] = cons_min[t]; }

#pragma unroll
    for (int off = 32; off > 0; off >>= 1) {
#pragma unroll
        for (int k = 0; k < 7; ++k) v[k] += __shfl_down(v[k], off);
    }
    __shared__ float red[4][7];
    int lane = t & 63, wid = t >> 6;
    if (lane == 0) {
#pragma unroll
        for (int k = 0; k < 7; ++k) red[wid][k] = v[k];
    }
    __syncthreads();
    if (t == 0) {
        float tot[7];
#pragma unroll
        for (int k = 0; k < 7; ++k)
            tot[k] = red[0][k] + red[1][k] + red[2][k] + red[3][k];
        float S_cg = tot[0], S_cs = tot[1], S_c = tot[2],
              S_g  = tot[3], S_s  = tot[4];
        float seg_tot = tot[5], cons_tot = tot[6];
        float dice1 = 1.f - (2.f * S_cg + SMOOTH) / (S_c + S_g + SMOOTH);
        float dice2 = 1.f - (2.f * S_cs + SMOOTH) / (S_c + S_s + SMOOTH);
        out[0] = dice1 + seg_tot + GAMMA * (dice2 + cons_tot);
    }
}

extern "C" void kernel_launch(void* const* d_in, const int* in_sizes, int n_in,
                              void* d_out, int out_size, void* d_ws, size_t ws_size,
                              hipStream_t stream) {
    const float* gt_mask = (const float*)d_in[0];   // [B,512,512]
    const float* gtc     = (const float*)d_in[1];   // [B,256,2]
    const float* sgs     = (const float*)d_in[2];   // [B,256,2]
    const float* scs     = (const float*)d_in[3];   // [B,256,2]
    const float* sn_mask = (const float*)d_in[4];   // [B,512,512]
    const float* cc      = (const float*)d_in[5];   // [B,256,2]
    const float* cl_mask = (const float*)d_in[6];   // [B,512,512]
    float* out = (float*)d_out;

    int B = in_sizes[1] / 512;                      // 64

    float* ws       = (float*)d_ws;
    float* psum     = ws;                           // 5 * MB_BLOCKS floats
    float* seg_min  = ws + 5 * MB_BLOCKS;           // B floats
    float* cons_min = seg_min + 64;                 // B floats

    hipLaunchKernelGGL(fused_kernel, dim3(MB_BLOCKS + NCONTOUR), dim3(256), 0, stream,
                       (const f32x4*)gt_mask, (const f32x4*)sn_mask,
                       (const f32x4*)cl_mask,
                       (const float2*)gtc, (const float2*)sgs,
                       (const float2*)scs, (const float2*)cc,
                       psum, seg_min, cons_min);
    hipLaunchKernelGGL(final_kernel, dim3(1), dim3(256), 0, stream,
                       psum, seg_min, cons_min, out, B);
}

// Round 10
// 45.680 us; speedup vs baseline: 1.4698x; 1.0104x over previous
//
#include <hip/hip_runtime.h>

#define GAMMA 0.5f
#define SMOOTH 1.0f
#define MB_BLOCKS 2048
#define NCONTOUR 64
#define CHUNK 8

typedef float f32x4 __attribute__((ext_vector_type(4)));

// ---------------------------------------------------------------------------
// Contour-path body: per-batch cyclic-shift MSE minima (one block = batch b).
// noinline keeps its regalloc/scheduling out of the mask path.
// ---------------------------------------------------------------------------
__device__ __attribute__((noinline)) void contour_body(
    const float2* __restrict__ gtc, const float2* __restrict__ sgs,
    const float2* __restrict__ scs, const float2* __restrict__ cc,
    float* __restrict__ seg_min, float* __restrict__ cons_min, int b)
{
    __shared__ float gx[256], gy[256];   // ground_truth_contour
    __shared__ float ax[256], ay[256];   // snake_GT_size
    __shared__ float px[256], py[256];   // snake_classic_size
    __shared__ float cx[256], cy[256];   // classic_contour
    int t = threadIdx.x;
    float2 v;
    v = gtc[b * 256 + t]; gx[t] = v.x; gy[t] = v.y;
    v = sgs[b * 256 + t]; ax[t] = v.x; ay[t] = v.y;
    v = scs[b * 256 + t]; px[t] = v.x; py[t] = v.y;
    v = cc [b * 256 + t]; cx[t] = v.x; cy[t] = v.y;
    __syncthreads();

    // shift-0 seg candidate compares snake_classic_size vs GT contour
    const float* sx = (t == 0) ? px : ax;
    const float* sy = (t == 0) ? py : ay;

    float seg = 0.f, cons = 0.f;
#pragma unroll 4
    for (int j = 0; j < 256; ++j) {
        int r = (j - t) & 255;
        float dx = sx[j] - gx[r];
        float dy = sy[j] - gy[r];
        seg += dx * dx + dy * dy;
        float ex = px[j] - cx[r];
        float ey = py[j] - cy[r];
        cons += ex * ex + ey * ey;
    }
    seg  *= (1.0f / 512.0f);
    cons *= (1.0f / 512.0f);

#pragma unroll
    for (int off = 32; off > 0; off >>= 1) {
        seg  = fminf(seg,  __shfl_down(seg,  off));
        cons = fminf(cons, __shfl_down(cons, off));
    }
    __shared__ float rs[4], rc[4];
    int lane = t & 63, wid = t >> 6;
    if (lane == 0) { rs[wid] = seg; rc[wid] = cons; }
    __syncthreads();
    if (t == 0) {
        seg_min[b]  = fminf(fminf(rs[0], rs[1]), fminf(rs[2], rs[3]));
        cons_min[b] = fminf(fminf(rc[0], rc[1]), fminf(rc[2], rc[3]));
    }
}

// ---------------------------------------------------------------------------
// Kernel A (fused): blocks [0, NCONTOUR) do contour minima; blocks
// [NCONTOUR, NCONTOUR+MB_BLOCKS) do the 5-way mask sums.
// Mask path (inlined): PLAIN loads (L3 retains all 201 MB across graph
// replays -- R2/R4 warm evidence) + R8's sched_group_barrier pin (forces
// the 24-deep burst) + amdgpu_waves_per_eu(4,4) so the allocator KNOWS
// occupancy is capped at 4 waves/EU and uses the full 128-VGPR budget
// (fixes R8's spill-against-64 and R2/R4/R7's VGPR~32 collapse).
// ---------------------------------------------------------------------------
__global__ __launch_bounds__(256)
__attribute__((amdgpu_waves_per_eu(4, 4)))
void fused_kernel(
    const f32x4* __restrict__ g4, const f32x4* __restrict__ s4,
    const f32x4* __restrict__ c4,
    const float2* __restrict__ gtc, const float2* __restrict__ sgs,
    const float2* __restrict__ scs, const float2* __restrict__ cc,
    float* __restrict__ psum, float* __restrict__ seg_min,
    float* __restrict__ cons_min)
{
    int bid = blockIdx.x;
    if (bid < NCONTOUR) {
        contour_body(gtc, sgs, scs, cc, seg_min, cons_min, bid);
        return;
    }

    int mbid = bid - NCONTOUR;
    int base = mbid * (256 * CHUNK) + threadIdx.x;

    f32x4 g[CHUNK], s[CHUNK], c[CHUNK];
#pragma unroll
    for (int k = 0; k < CHUNK; ++k) g[k] = g4[base + k * 256];
#pragma unroll
    for (int k = 0; k < CHUNK; ++k) s[k] = s4[base + k * 256];
#pragma unroll
    for (int k = 0; k < CHUNK; ++k) c[k] = c4[base + k * 256];

    float s_cg = 0.f, s_cs = 0.f, s_c = 0.f, s_g = 0.f, s_s = 0.f;
#pragma unroll
    for (int k = 0; k < CHUNK; ++k) {
        s_cg += c[k].x * g[k].x + c[k].y * g[k].y + c[k].z * g[k].z + c[k].w * g[k].w;
        s_cs += c[k].x * s[k].x + c[k].y * s[k].y + c[k].z * s[k].z + c[k].w * s[k].w;
        s_c  += c[k].x + c[k].y + c[k].z + c[k].w;
        s_g  += g[k].x + g[k].y + g[k].z + g[k].w;
        s_s  += s[k].x + s[k].y + s[k].z + s[k].w;
    }

    // T19 pin (R8-proven to force the burst): addr VALU -> 24 VMEM_READ
    // back-to-back -> FMA block.
    __builtin_amdgcn_sched_group_barrier(0x002, 16, 0);   // VALU (addr)
    __builtin_amdgcn_sched_group_barrier(0x020, 24, 0);   // VMEM_READ x24
    __builtin_amdgcn_sched_group_barrier(0x002, 200, 0);  // VALU (FMAs)

#pragma unroll
    for (int off = 32; off > 0; off >>= 1) {
        s_cg += __shfl_down(s_cg, off);
        s_cs += __shfl_down(s_cs, off);
        s_c  += __shfl_down(s_c,  off);
        s_g  += __shfl_down(s_g,  off);
        s_s  += __shfl_down(s_s,  off);
    }
    __shared__ float red[4][5];
    int lane = threadIdx.x & 63;
    int wid  = threadIdx.x >> 6;
    if (lane == 0) {
        red[wid][0] = s_cg; red[wid][1] = s_cs; red[wid][2] = s_c;
        red[wid][3] = s_g;  red[wid][4] = s_s;
    }
    __syncthreads();
    if (threadIdx.x == 0) {
#pragma unroll
        for (int k = 0; k < 5; ++k) {
            float a = red[0][k] + red[1][k] + red[2][k] + red[3][k];
            psum[k * MB_BLOCKS + mbid] = a;
        }
    }
}

// ---------------------------------------------------------------------------
// Kernel B: finalize. One combined 7-value reduction (5 mask sums + seg +
// cons), then compose the scalar loss.
// ---------------------------------------------------------------------------
__global__ __launch_bounds__(256) void final_kernel(
    const float* __restrict__ psum, const float* __restrict__ seg_min,
    const float* __restrict__ cons_min, float* __restrict__ out, int B)
{
    int t = threadIdx.x;
    float v[7] = {0.f, 0.f, 0.f, 0.f, 0.f, 0.f, 0.f};

#pragma unroll
    for (int k = 0; k < 5; ++k)
        for (int i = t; i < MB_BLOCKS; i += 256)
            v[k] += psum[k * MB_BLOCKS + i];
    if (t < B) { v[5] = seg_min[t]; v[6] = cons_min[t]; }

#pragma unroll
    for (int off = 32; off > 0; off >>= 1) {
#pragma unroll
        for (int k = 0; k < 7; ++k) v[k] += __shfl_down(v[k], off);
    }
    __shared__ float red[4][7];
    int lane = t & 63, wid = t >> 6;
    if (lane == 0) {
#pragma unroll
        for (int k = 0; k < 7; ++k) red[wid][k] = v[k];
    }
    __syncthreads();
    if (t == 0) {
        float tot[7];
#pragma unroll
        for (int k = 0; k < 7; ++k)
            tot[k] = red[0][k] + red[1][k] + red[2][k] + red[3][k];
        float S_cg = tot[0], S_cs = tot[1], S_c = tot[2],
              S_g  = tot[3], S_s  = tot[4];
        float seg_tot = tot[5], cons_tot = tot[6];
        float dice1 = 1.f - (2.f * S_cg + SMOOTH) / (S_c + S_g + SMOOTH);
        float dice2 = 1.f - (2.f * S_cs + SMOOTH) / (S_c + S_s + SMOOTH);
        out[0] = dice1 + seg_tot + GAMMA * (dice2 + cons_tot);
    }
}

extern "C" void kernel_launch(void* const* d_in, const int* in_sizes, int n_in,
                              void* d_out, int out_size, void* d_ws, size_t ws_size,
                              hipStream_t stream) {
    const float* gt_mask = (const float*)d_in[0];   // [B,512,512]
    const float* gtc     = (const float*)d_in[1];   // [B,256,2]
    const float* sgs     = (const float*)d_in[2];   // [B,256,2]
    const float* scs     = (const float*)d_in[3];   // [B,256,2]
    const float* sn_mask = (const float*)d_in[4];   // [B,512,512]
    const float* cc      = (const float*)d_in[5];   // [B,256,2]
    const float* cl_mask = (const float*)d_in[6];   // [B,512,512]
    float* out = (float*)d_out;

    int B = in_sizes[1] / 512;                      // 64

    float* ws       = (float*)d_ws;
    float* psum     = ws;                           // 5 * MB_BLOCKS floats
    float* seg_min  = ws + 5 * MB_BLOCKS;           // B floats
    float* cons_min = seg_min + 64;                 // B floats

    hipLaunchKernelGGL(fused_kernel, dim3(MB_BLOCKS + NCONTOUR), dim3(256), 0, stream,
                       (const f32x4*)gt_mask, (const f32x4*)sn_mask,
                       (const f32x4*)cl_mask,
                       (const float2*)gtc, (const float2*)sgs,
                       (const float2*)scs, (const float2*)cc,
                       psum, seg_min, cons_min);
    hipLaunchKernelGGL(final_kernel, dim3(1), dim3(256), 0, stream,
                       psum, seg_min, cons_min, out, B);
}